// Round 12
// baseline (456.973 us; speedup 1.0000x reference)
//
#include <hip/hip_runtime.h>
#include <hip/hip_fp16.h>

#define N_NODES 200000
#define N_EDGES 3200000
#define N_PAIRS 1000000
#define DIM 64
#define CAP 48                  // slots per node (max degree ~38 for Poisson(16))
#define NPB 256                 // nodes per fine bucket  (fine bucket = col >> 8)
#define NB 782                  // ceil(N_NODES / NPB)
#define BKTCAP 5120             // fine staging capacity per bucket
#define BSTRIDE 16              // padded counters: one per 64B line

// two-level partition
#define CBITS 11
#define NBC 98                  // ceil(200000 / 2048) coarse buckets
#define BKTCAPA 34816           // coarse staging cap (mean 32768 + 11 sigma)
#define CHUNKA 4096
#define NBLKA ((N_EDGES + CHUNKA - 1) / CHUNKA)   // 782
#define BUFB 4400               // >= ceil(BKTCAPA/8)

// ---- pass A: counting-sort 4096 edges by coarse bucket, coalesced streamout ----
__global__ void partA_kernel(const int* __restrict__ row, const int* __restrict__ col,
                             int* __restrict__ bktcntA, unsigned* __restrict__ stagingA, int E) {
    __shared__ unsigned buf[CHUNKA];          // 16 KB
    __shared__ int cntA[128], offA[128];
    __shared__ int curA[NBC], baseA[NBC];
    int tid = threadIdx.x;
    for (int i = tid; i < 128; i += 256) cntA[i] = 0;
    __syncthreads();
    int start = blockIdx.x * CHUNKA;
    unsigned pk[16];
    int bk[16];
    #pragma unroll
    for (int k = 0; k < 16; ++k) {
        int e = start + k * 256 + tid;
        if (e < E) {
            int c = col[e];
            int r = row[e];
            pk[k] = ((unsigned)(c & 2047) << 18) | (unsigned)r;   // col_local(11b) | row(18b)
            bk[k] = c >> CBITS;
            atomicAdd(&cntA[bk[k]], 1);
        } else bk[k] = -1;
    }
    __syncthreads();
    // inclusive scan over 128 (Hillis-Steele), then exclusive
    if (tid < 128) offA[tid] = cntA[tid];
    __syncthreads();
    for (int d = 1; d < 128; d <<= 1) {
        int v = 0;
        if (tid < 128 && tid >= d) v = offA[tid - d];
        __syncthreads();
        if (tid < 128) offA[tid] += v;
        __syncthreads();
    }
    if (tid < NBC) {
        int x = offA[tid] - cntA[tid];        // exclusive offset
        curA[tid] = x;
        offA[tid] = x;
        baseA[tid] = (cntA[tid] > 0) ? atomicAdd(&bktcntA[tid * BSTRIDE], cntA[tid]) : 0;
    }
    __syncthreads();
    #pragma unroll
    for (int k = 0; k < 16; ++k) {
        if (bk[k] >= 0) {
            int p = atomicAdd(&curA[bk[k]], 1);
            buf[p] = pk[k];
        }
    }
    __syncthreads();
    // coalesced per-bucket streamout (runs avg ~42 elements)
    for (int b = 0; b < NBC; ++b) {
        int n = cntA[b];
        if (n == 0) continue;
        int base = baseA[b];
        if (base + n > BKTCAPA) n = max(0, BKTCAPA - base);
        unsigned* dst = stagingA + (size_t)b * BKTCAPA + base;
        const int o = offA[b];
        for (int i = tid; i < n; i += 256) dst[i] = buf[o + i];
    }
}

// ---- pass B: slice a coarse bucket, 3-bit sort to 8 fine buckets, coalesced out ----
__global__ void partB_kernel(const unsigned* __restrict__ stagingA, const int* __restrict__ bktcntA,
                             int* __restrict__ bktcntB, unsigned* __restrict__ stagingB) {
    __shared__ unsigned buf[BUFB];            // 17.6 KB
    __shared__ int cntB[8], offB[8], curB[8], baseB[8];
    int bc = blockIdx.x >> 3;
    int s  = blockIdx.x & 7;
    int tid = threadIdx.x;
    if (tid < 8) cntB[tid] = 0;
    __syncthreads();
    int cnt = min(bktcntA[bc * BSTRIDE], BKTCAPA);
    int slice = (cnt + 7) >> 3;
    int lo = s * slice;
    int hi = min(lo + slice, cnt);
    int n = max(hi - lo, 0);                  // <= 4352 < BUFB
    const unsigned* src = stagingA + (size_t)bc * BKTCAPA + lo;
    for (int i = tid; i < n; i += 256) atomicAdd(&cntB[src[i] >> 26], 1);
    __syncthreads();
    if (tid == 0) {
        int a = 0;
        for (int b = 0; b < 8; ++b) { offB[b] = a; a += cntB[b]; }
    }
    __syncthreads();
    if (tid < 8) {
        curB[tid] = offB[tid];
        baseB[tid] = (cntB[tid] > 0) ? atomicAdd(&bktcntB[(bc * 8 + tid) * BSTRIDE], cntB[tid]) : 0;
    }
    __syncthreads();
    for (int i = tid; i < n; i += 256) {
        unsigned e = src[i];
        int fb = e >> 26;
        int p = atomicAdd(&curB[fb], 1);
        buf[p] = e & 0x3FFFFFFu;              // keep col&255 (bits 18..25) | row
    }
    __syncthreads();
    for (int b = 0; b < 8; ++b) {
        int m = cntB[b];
        if (m == 0) continue;
        int base = baseB[b];
        if (base + m > BKTCAP) m = max(0, BKTCAP - base);
        unsigned* dst = stagingB + (size_t)(bc * 8 + b) * BKTCAP + base;
        const int o = offB[b];
        for (int i = tid; i < m; i += 256) dst[i] = buf[o + i];
    }
}

// ---- pass 2: one block per fine bucket; scatter staged edges into an LDS tile,
//      then per-node insertion sort by source id (ascending) so the props sweep
//      the x-table in a synchronized ascending band (L2-locality). ----
__global__ void build_kernel(const unsigned* __restrict__ staging, const int* __restrict__ bktcnt,
                             int* __restrict__ srcrow, int* __restrict__ deg,
                             float* __restrict__ dinv, int N) {
    __shared__ int tile[NPB * CAP];   // 48 KB
    __shared__ int cur[NPB];
    int b = blockIdx.x;
    for (int i = threadIdx.x; i < NPB; i += 256) cur[i] = 0;
    __syncthreads();
    int cnt = min(bktcnt[b * BSTRIDE], BKTCAP);
    const unsigned* st = staging + (size_t)b * BKTCAP;
    for (int i = threadIdx.x; i < cnt; i += 256) {
        unsigned packed = st[i];
        int r = packed & 0x3FFFF;
        int cl = packed >> 18;
        int p = atomicAdd(&cur[cl], 1);
        if (p < CAP) tile[cl * CAP + p] = r;
    }
    __syncthreads();
    // per-node insertion sort by src id (one thread per node, list in LDS)
    {
        int i = threadIdx.x;             // NPB == 256 == blockDim.x
        int d = min(cur[i], CAP);
        int* a = &tile[i * CAP];
        for (int u = 1; u < d; ++u) {
            int key = a[u];
            int v = u - 1;
            while (v >= 0 && a[v] > key) { a[v + 1] = a[v]; --v; }
            a[v + 1] = key;
        }
    }
    __syncthreads();
    int nodeBase = b * NPB;
    int nvalid = min(NPB, N - nodeBase);
    for (int i = threadIdx.x; i < nvalid; i += 256) {
        int d = min(cur[i], CAP);
        deg[nodeBase + i] = d;
        dinv[nodeBase + i] = (d > 0) ? rsqrtf((float)d) : 0.0f;
    }
    int tot = nvalid * CAP;
    int* dst = srcrow + (size_t)nodeBase * CAP;
    for (int i = threadIdx.x; i < tot; i += 256) dst[i] = tile[i];
}

// ---- one-time pack: ew[s] = src_id | (in_deg(src) << 18); 0 for padding slots. ----
__global__ void ewpack_kernel(unsigned int* __restrict__ ew, const int* __restrict__ deg,
                              int total) {
    int s = blockIdx.x * blockDim.x + threadIdx.x;
    if (s >= total) return;
    int n = s / CAP;
    int l = s - n * CAP;
    unsigned int e = 0;
    if (l < deg[n]) {
        int r = (int)ew[s];                    // srcrow id
        e = (unsigned int)r | ((unsigned int)deg[r] << 18);
    }
    ew[s] = e;
}

// ---- emb fp32 -> fp16 ----
__global__ void convert_kernel(const float2* __restrict__ x, __half2* __restrict__ y, int n2) {
    int i = blockIdx.x * blockDim.x + threadIdx.x;
    if (i < n2) {
        float2 v = x[i];
        y[i] = __floats2half2_rn(v.x, v.y);
    }
}

__device__ __forceinline__ float2 h2f(unsigned int u) {
    __half2 h = *(__half2*)&u;
    return __half22float2(h);
}

// ---- propagation: one wave per node; 16 lanes per row (4 dims each, uint2 load);
//      4 edges concurrent via quarter-wave groups; (id,w) broadcast from LDS. ----
__global__ void prop_kernel(const uint2* __restrict__ x, const unsigned int* __restrict__ ew,
                            const int* __restrict__ deg, const float* __restrict__ dinv,
                            uint2* __restrict__ xn, int N) {
    __shared__ int2 lds[4][CAP];          // 1.5 KB
    int wv = threadIdx.x >> 6;
    int n = blockIdx.x * 4 + wv;
    int l = threadIdx.x & 63;
    int q = l & 15;
    int quarter = l >> 4;
    int cnt = deg[n];
    if (l < CAP) {
        unsigned int e = ew[(unsigned int)n * CAP + l];
        int id = e & 0x3FFFF;
        int dr = e >> 18;
        float w = dr ? rsqrtf((float)dr) : 0.0f;
        lds[wv][l] = make_int2(id, __float_as_int(w));
    }
    __syncthreads();
    float a0 = 0.f, a1 = 0.f, a2 = 0.f, a3 = 0.f;
    int trips = (cnt + 3) >> 2;
    #pragma unroll 4
    for (int k = 0; k < trips; ++k) {
        int2 e = lds[wv][k * 4 + quarter];
        float w = __int_as_float(e.y);
        uint2 pix = x[(unsigned int)e.x * 16u + q];
        float2 flo = h2f(pix.x);
        float2 fhi = h2f(pix.y);
        a0 += flo.x * w; a1 += flo.y * w;
        a2 += fhi.x * w; a3 += fhi.y * w;
    }
    a0 += __shfl_xor(a0, 16, 64); a1 += __shfl_xor(a1, 16, 64);
    a2 += __shfl_xor(a2, 16, 64); a3 += __shfl_xor(a3, 16, 64);
    a0 += __shfl_xor(a0, 32, 64); a1 += __shfl_xor(a1, 32, 64);
    a2 += __shfl_xor(a2, 32, 64); a3 += __shfl_xor(a3, 32, 64);
    float dn = dinv[n];
    if (quarter == 0) {
        __half2 o01 = __floats2half2_rn(a0 * dn, a1 * dn);
        __half2 o23 = __floats2half2_rn(a2 * dn, a3 * dn);
        uint2 out;
        out.x = *(unsigned int*)&o01;
        out.y = *(unsigned int*)&o23;
        xn[(unsigned int)n * 16u + q] = out;
    }
}

// ---- layer-3 propagation with fused alpha-combine epilogue ----
__global__ void prop_final_kernel(const uint2* __restrict__ x, const unsigned int* __restrict__ ew,
                                  const int* __restrict__ deg, const float* __restrict__ dinv,
                                  const uint2* __restrict__ h0, const uint2* __restrict__ h1,
                                  const float* __restrict__ alpha,
                                  uint2* __restrict__ outh, int N) {
    __shared__ int2 lds[4][CAP];
    int wv = threadIdx.x >> 6;
    int n = blockIdx.x * 4 + wv;
    int l = threadIdx.x & 63;
    int q = l & 15;
    int quarter = l >> 4;
    int cnt = deg[n];
    if (l < CAP) {
        unsigned int e = ew[(unsigned int)n * CAP + l];
        int id = e & 0x3FFFF;
        int dr = e >> 18;
        float w = dr ? rsqrtf((float)dr) : 0.0f;
        lds[wv][l] = make_int2(id, __float_as_int(w));
    }
    __syncthreads();
    float a0 = 0.f, a1 = 0.f, a2 = 0.f, a3 = 0.f;
    int trips = (cnt + 3) >> 2;
    #pragma unroll 4
    for (int k = 0; k < trips; ++k) {
        int2 e = lds[wv][k * 4 + quarter];
        float w = __int_as_float(e.y);
        uint2 pix = x[(unsigned int)e.x * 16u + q];
        float2 flo = h2f(pix.x);
        float2 fhi = h2f(pix.y);
        a0 += flo.x * w; a1 += flo.y * w;
        a2 += fhi.x * w; a3 += fhi.y * w;
    }
    a0 += __shfl_xor(a0, 16, 64); a1 += __shfl_xor(a1, 16, 64);
    a2 += __shfl_xor(a2, 16, 64); a3 += __shfl_xor(a3, 16, 64);
    a0 += __shfl_xor(a0, 32, 64); a1 += __shfl_xor(a1, 32, 64);
    a2 += __shfl_xor(a2, 32, 64); a3 += __shfl_xor(a3, 32, 64);
    float dn = dinv[n];
    if (quarter == 0) {
        float al0 = alpha[0], al1 = alpha[1], al2 = alpha[2], al3 = alpha[3];
        unsigned int idx = (unsigned int)n * 16u + q;
        uint2 p0 = h0[idx];
        uint2 p1 = h1[idx];
        uint2 p2 = x[idx];
        float2 f0l = h2f(p0.x), f0h = h2f(p0.y);
        float2 f1l = h2f(p1.x), f1h = h2f(p1.y);
        float2 f2l = h2f(p2.x), f2h = h2f(p2.y);
        float r0 = al0 * f0l.x + al1 * f1l.x + al2 * f2l.x + al3 * (a0 * dn);
        float r1 = al0 * f0l.y + al1 * f1l.y + al2 * f2l.y + al3 * (a1 * dn);
        float r2 = al0 * f0h.x + al1 * f1h.x + al2 * f2h.x + al3 * (a2 * dn);
        float r3 = al0 * f0h.y + al1 * f1h.y + al2 * f2h.y + al3 * (a3 * dn);
        __half2 o01 = __floats2half2_rn(r0, r1);
        __half2 o23 = __floats2half2_rn(r2, r3);
        uint2 out;
        out.x = *(unsigned int*)&o01;
        out.y = *(unsigned int*)&o23;
        outh[idx] = out;
    }
}

// ---- 16 lanes per TWO pairs (p and p+P/2), 8B fp16 loads, shfl reduce ----
__global__ void dot_kernel(const uint2* __restrict__ outh, const int* __restrict__ pa,
                           const int* __restrict__ pb, float* __restrict__ res, int P) {
    int t = blockIdx.x * blockDim.x + threadIdx.x;
    int g = t >> 4;
    int l = threadIdx.x & 15;
    int half = P >> 1;                 // P is even (1M)
    if (g >= half) return;
    int p0 = g, p1 = g + half;
    int a0 = pa[p0], b0 = pb[p0];
    int a1 = pa[p1], b1 = pb[p1];
    uint2 ua0 = outh[(size_t)a0 * 16 + l];
    uint2 ub0 = outh[(size_t)b0 * 16 + l];
    uint2 ua1 = outh[(size_t)a1 * 16 + l];
    uint2 ub1 = outh[(size_t)b1 * 16 + l];
    float2 fx0 = h2f(ua0.x), fx1 = h2f(ua0.y);
    float2 fy0 = h2f(ub0.x), fy1 = h2f(ub0.y);
    float s0 = fx0.x * fy0.x + fx0.y * fy0.y + fx1.x * fy1.x + fx1.y * fy1.y;
    float2 fu0 = h2f(ua1.x), fu1 = h2f(ua1.y);
    float2 fv0 = h2f(ub1.x), fv1 = h2f(ub1.y);
    float s1 = fu0.x * fv0.x + fu0.y * fv0.y + fu1.x * fv1.x + fu1.y * fv1.y;
    s0 += __shfl_xor(s0, 1, 64);
    s1 += __shfl_xor(s1, 1, 64);
    s0 += __shfl_xor(s0, 2, 64);
    s1 += __shfl_xor(s1, 2, 64);
    s0 += __shfl_xor(s0, 4, 64);
    s1 += __shfl_xor(s1, 4, 64);
    s0 += __shfl_xor(s0, 8, 64);
    s1 += __shfl_xor(s1, 8, 64);
    if (l == 0) {
        res[p0] = s0;
        res[p1] = s1;
    }
}

extern "C" void kernel_launch(void* const* d_in, const int* in_sizes, int n_in,
                              void* d_out, int out_size, void* d_ws, size_t ws_size,
                              hipStream_t stream) {
    const float* emb   = (const float*)d_in[0];
    const float* alpha = (const float*)d_in[1];
    const int*   ei    = (const int*)d_in[2];
    const int*   eli   = (const int*)d_in[3];
    const int* row = ei;                // edge_index[0] = source
    const int* col = ei + N_EDGES;      // edge_index[1] = target
    const int* pa  = eli;
    const int* pb  = eli + N_PAIRS;
    float* res = (float*)d_out;

    const size_t hfeat_bytes = (size_t)N_NODES * DIM * sizeof(__half); // 25.6 MB
    char* ws = (char*)d_ws;
    size_t off = 0;
    auto alloc = [&](size_t bytes) {
        void* p = ws + off;
        off += (bytes + 255) & ~(size_t)255;
        return p;
    };
    int*      bktcntA  = (int*)alloc((size_t)NBC * BSTRIDE * sizeof(int));
    int*      bktcntB  = (int*)alloc((size_t)NB * BSTRIDE * sizeof(int));
    unsigned* stagingA = (unsigned*)alloc((size_t)NBC * BKTCAPA * sizeof(unsigned)); // 13.6 MB
    unsigned* stagingB = (unsigned*)alloc((size_t)NB * BKTCAP * sizeof(unsigned));   // 16 MB
    int*      srcrow   = (int*)alloc((size_t)N_NODES * CAP * sizeof(int));           // 38.4 MB (reused as ew)
    int*      deg      = (int*)alloc((size_t)N_NODES * sizeof(int));
    float*    dinv     = (float*)alloc((size_t)N_NODES * sizeof(float));
    __half*   h0       = (__half*)alloc(hfeat_bytes);
    __half*   h1       = (__half*)alloc(hfeat_bytes);
    __half*   h2       = (__half*)alloc(hfeat_bytes);
    __half*   outh     = (__half*)alloc(hfeat_bytes);
    unsigned int* ew = (unsigned int*)srcrow;   // in-place repack

    // ---- CSR build: 2-level coalesced partition + LDS-tile scatter + ew pack ----
    hipMemsetAsync(bktcntA, 0, (size_t)NBC * BSTRIDE * sizeof(int), stream);
    hipMemsetAsync(bktcntB, 0, (size_t)NB * BSTRIDE * sizeof(int), stream);
    partA_kernel<<<NBLKA, 256, 0, stream>>>(row, col, bktcntA, stagingA, N_EDGES);
    partB_kernel<<<NBC * 8, 256, 0, stream>>>(stagingA, bktcntA, bktcntB, stagingB);
    build_kernel<<<NB, 256, 0, stream>>>(stagingB, bktcntB, srcrow, deg, dinv, N_NODES);
    const int total_slots = N_NODES * CAP;
    ewpack_kernel<<<(total_slots + 255) / 256, 256, 0, stream>>>(ew, deg, total_slots);

    // ---- emb -> fp16 h0 ----
    const int n2 = N_NODES * DIM / 2;
    convert_kernel<<<(n2 + 255) / 256, 256, 0, stream>>>((const float2*)emb, (__half2*)h0, n2);

    // ---- 3 propagation layers; layer 3 fuses the alpha-combine ----
    const int prop_grid = N_NODES / 4;   // 4 waves/block, 1 node/wave
    prop_kernel<<<prop_grid, 256, 0, stream>>>((const uint2*)h0, ew, deg, dinv, (uint2*)h1, N_NODES);
    prop_kernel<<<prop_grid, 256, 0, stream>>>((const uint2*)h1, ew, deg, dinv, (uint2*)h2, N_NODES);
    prop_final_kernel<<<prop_grid, 256, 0, stream>>>((const uint2*)h2, ew, deg, dinv,
                                                     (const uint2*)h0, (const uint2*)h1,
                                                     alpha, (uint2*)outh, N_NODES);

    // ---- pair dot products on fp16 rows (2 pairs / 16-lane group) ----
    dot_kernel<<<((size_t)(N_PAIRS / 2) * 16 + 255) / 256, 256, 0, stream>>>(
        (const uint2*)outh, pa, pb, res, N_PAIRS);
}

// Round 13
// 431.837 us; speedup vs baseline: 1.0582x; 1.0582x over previous
//
#include <hip/hip_runtime.h>
#include <hip/hip_fp16.h>

#define N_NODES 200000
#define N_EDGES 3200000
#define N_PAIRS 1000000
#define DIM 64
#define CAP 48                  // slots per node (max degree ~38 for Poisson(16))
#define NPB 256                 // nodes per fine bucket  (fine bucket = col >> 8)
#define NB 782                  // ceil(N_NODES / NPB)
#define BSTRIDE 16              // padded counters: one per 64B line

// coarse partition
#define CBITS 11
#define NBC 98                  // ceil(200000 / 2048) coarse buckets
#define BKTCAPA 34816           // coarse staging cap (mean 32768 + 11 sigma)
#define CHUNKA 4096
#define NBLKA ((N_EDGES + CHUNKA - 1) / CHUNKA)   // 782

// ---- pass A: counting-sort 4096 edges by coarse bucket, coalesced streamout ----
__global__ void partA_kernel(const int* __restrict__ row, const int* __restrict__ col,
                             int* __restrict__ bktcntA, unsigned* __restrict__ stagingA, int E) {
    __shared__ unsigned buf[CHUNKA];          // 16 KB
    __shared__ int cntA[128], offA[128];
    __shared__ int curA[NBC], baseA[NBC];
    int tid = threadIdx.x;
    for (int i = tid; i < 128; i += 256) cntA[i] = 0;
    __syncthreads();
    int start = blockIdx.x * CHUNKA;
    unsigned pk[16];
    int bk[16];
    #pragma unroll
    for (int k = 0; k < 16; ++k) {
        int e = start + k * 256 + tid;
        if (e < E) {
            int c = col[e];
            int r = row[e];
            pk[k] = ((unsigned)(c & 2047) << 18) | (unsigned)r;   // col_local(11b) | row(18b)
            bk[k] = c >> CBITS;
            atomicAdd(&cntA[bk[k]], 1);
        } else bk[k] = -1;
    }
    __syncthreads();
    // inclusive scan over 128 (Hillis-Steele), then exclusive
    if (tid < 128) offA[tid] = cntA[tid];
    __syncthreads();
    for (int d = 1; d < 128; d <<= 1) {
        int v = 0;
        if (tid < 128 && tid >= d) v = offA[tid - d];
        __syncthreads();
        if (tid < 128) offA[tid] += v;
        __syncthreads();
    }
    if (tid < NBC) {
        int x = offA[tid] - cntA[tid];        // exclusive offset
        curA[tid] = x;
        offA[tid] = x;
        baseA[tid] = (cntA[tid] > 0) ? atomicAdd(&bktcntA[tid * BSTRIDE], cntA[tid]) : 0;
    }
    __syncthreads();
    #pragma unroll
    for (int k = 0; k < 16; ++k) {
        if (bk[k] >= 0) {
            int p = atomicAdd(&curA[bk[k]], 1);
            buf[p] = pk[k];
        }
    }
    __syncthreads();
    // coalesced per-bucket streamout (runs avg ~42 elements)
    for (int b = 0; b < NBC; ++b) {
        int n = cntA[b];
        if (n == 0) continue;
        int base = baseA[b];
        if (base + n > BKTCAPA) n = max(0, BKTCAPA - base);
        unsigned* dst = stagingA + (size_t)b * BKTCAPA + base;
        const int o = offA[b];
        for (int i = tid; i < n; i += 256) dst[i] = buf[o + i];
    }
}

// ---- fused build: one block per fine bucket; scan the parent coarse bucket
//      directly, filter by fine-index bits 26..28, LDS-tile scatter, write out. ----
__global__ void build_kernel(const unsigned* __restrict__ stagingA, const int* __restrict__ bktcntA,
                             int* __restrict__ srcrow, int* __restrict__ deg,
                             float* __restrict__ dinv, int N) {
    __shared__ int tile[NPB * CAP];   // 48 KB
    __shared__ int cur[NPB];
    int b = blockIdx.x;
    int bc = b >> 3;
    unsigned fb = (unsigned)(b & 7);
    for (int i = threadIdx.x; i < NPB; i += 256) cur[i] = 0;
    __syncthreads();
    int cnt = min(bktcntA[bc * BSTRIDE], BKTCAPA);
    const unsigned* st = stagingA + (size_t)bc * BKTCAPA;
    for (int i = threadIdx.x; i < cnt; i += 256) {
        unsigned e = st[i];
        if ((e >> 26) == fb) {
            int cl = (e >> 18) & 255;
            int p = atomicAdd(&cur[cl], 1);
            if (p < CAP) tile[cl * CAP + p] = (int)(e & 0x3FFFFu);
        }
    }
    __syncthreads();
    int nodeBase = b * NPB;
    int nvalid = min(NPB, N - nodeBase);
    for (int i = threadIdx.x; i < nvalid; i += 256) {
        int d = min(cur[i], CAP);
        deg[nodeBase + i] = d;
        dinv[nodeBase + i] = (d > 0) ? rsqrtf((float)d) : 0.0f;
    }
    int tot = nvalid * CAP;
    int* dst = srcrow + (size_t)nodeBase * CAP;
    for (int i = threadIdx.x; i < tot; i += 256) dst[i] = tile[i];
}

// ---- one-time pack: ew[s] = src_id | (in_deg(src) << 18); 0 for padding slots. ----
__global__ void ewpack_kernel(unsigned int* __restrict__ ew, const int* __restrict__ deg,
                              int total) {
    int s = blockIdx.x * blockDim.x + threadIdx.x;
    if (s >= total) return;
    int n = s / CAP;
    int l = s - n * CAP;
    unsigned int e = 0;
    if (l < deg[n]) {
        int r = (int)ew[s];                    // srcrow id
        e = (unsigned int)r | ((unsigned int)deg[r] << 18);
    }
    ew[s] = e;
}

// ---- emb fp32 -> fp16 ----
__global__ void convert_kernel(const float2* __restrict__ x, __half2* __restrict__ y, int n2) {
    int i = blockIdx.x * blockDim.x + threadIdx.x;
    if (i < n2) {
        float2 v = x[i];
        y[i] = __floats2half2_rn(v.x, v.y);
    }
}

__device__ __forceinline__ float2 h2f(unsigned int u) {
    __half2 h = *(__half2*)&u;
    return __half22float2(h);
}

// ---- propagation: one wave per node; 16 lanes per row (4 dims each, uint2 load);
//      4 edges concurrent via quarter-wave groups; (id,w) broadcast from LDS. ----
__global__ void prop_kernel(const uint2* __restrict__ x, const unsigned int* __restrict__ ew,
                            const int* __restrict__ deg, const float* __restrict__ dinv,
                            uint2* __restrict__ xn, int N) {
    __shared__ int2 lds[4][CAP];          // 1.5 KB
    int wv = threadIdx.x >> 6;
    int n = blockIdx.x * 4 + wv;
    int l = threadIdx.x & 63;
    int q = l & 15;
    int quarter = l >> 4;
    int cnt = deg[n];
    if (l < CAP) {
        unsigned int e = ew[(unsigned int)n * CAP + l];
        int id = e & 0x3FFFF;
        int dr = e >> 18;
        float w = dr ? rsqrtf((float)dr) : 0.0f;
        lds[wv][l] = make_int2(id, __float_as_int(w));
    }
    __syncthreads();
    float a0 = 0.f, a1 = 0.f, a2 = 0.f, a3 = 0.f;
    int trips = (cnt + 3) >> 2;
    #pragma unroll 4
    for (int k = 0; k < trips; ++k) {
        int2 e = lds[wv][k * 4 + quarter];
        float w = __int_as_float(e.y);
        uint2 pix = x[(unsigned int)e.x * 16u + q];
        float2 flo = h2f(pix.x);
        float2 fhi = h2f(pix.y);
        a0 += flo.x * w; a1 += flo.y * w;
        a2 += fhi.x * w; a3 += fhi.y * w;
    }
    a0 += __shfl_xor(a0, 16, 64); a1 += __shfl_xor(a1, 16, 64);
    a2 += __shfl_xor(a2, 16, 64); a3 += __shfl_xor(a3, 16, 64);
    a0 += __shfl_xor(a0, 32, 64); a1 += __shfl_xor(a1, 32, 64);
    a2 += __shfl_xor(a2, 32, 64); a3 += __shfl_xor(a3, 32, 64);
    float dn = dinv[n];
    if (quarter == 0) {
        __half2 o01 = __floats2half2_rn(a0 * dn, a1 * dn);
        __half2 o23 = __floats2half2_rn(a2 * dn, a3 * dn);
        uint2 out;
        out.x = *(unsigned int*)&o01;
        out.y = *(unsigned int*)&o23;
        xn[(unsigned int)n * 16u + q] = out;
    }
}

// ---- layer-3 propagation with fused alpha-combine epilogue ----
__global__ void prop_final_kernel(const uint2* __restrict__ x, const unsigned int* __restrict__ ew,
                                  const int* __restrict__ deg, const float* __restrict__ dinv,
                                  const uint2* __restrict__ h0, const uint2* __restrict__ h1,
                                  const float* __restrict__ alpha,
                                  uint2* __restrict__ outh, int N) {
    __shared__ int2 lds[4][CAP];
    int wv = threadIdx.x >> 6;
    int n = blockIdx.x * 4 + wv;
    int l = threadIdx.x & 63;
    int q = l & 15;
    int quarter = l >> 4;
    int cnt = deg[n];
    if (l < CAP) {
        unsigned int e = ew[(unsigned int)n * CAP + l];
        int id = e & 0x3FFFF;
        int dr = e >> 18;
        float w = dr ? rsqrtf((float)dr) : 0.0f;
        lds[wv][l] = make_int2(id, __float_as_int(w));
    }
    __syncthreads();
    float a0 = 0.f, a1 = 0.f, a2 = 0.f, a3 = 0.f;
    int trips = (cnt + 3) >> 2;
    #pragma unroll 4
    for (int k = 0; k < trips; ++k) {
        int2 e = lds[wv][k * 4 + quarter];
        float w = __int_as_float(e.y);
        uint2 pix = x[(unsigned int)e.x * 16u + q];
        float2 flo = h2f(pix.x);
        float2 fhi = h2f(pix.y);
        a0 += flo.x * w; a1 += flo.y * w;
        a2 += fhi.x * w; a3 += fhi.y * w;
    }
    a0 += __shfl_xor(a0, 16, 64); a1 += __shfl_xor(a1, 16, 64);
    a2 += __shfl_xor(a2, 16, 64); a3 += __shfl_xor(a3, 16, 64);
    a0 += __shfl_xor(a0, 32, 64); a1 += __shfl_xor(a1, 32, 64);
    a2 += __shfl_xor(a2, 32, 64); a3 += __shfl_xor(a3, 32, 64);
    float dn = dinv[n];
    if (quarter == 0) {
        float al0 = alpha[0], al1 = alpha[1], al2 = alpha[2], al3 = alpha[3];
        unsigned int idx = (unsigned int)n * 16u + q;
        uint2 p0 = h0[idx];
        uint2 p1 = h1[idx];
        uint2 p2 = x[idx];
        float2 f0l = h2f(p0.x), f0h = h2f(p0.y);
        float2 f1l = h2f(p1.x), f1h = h2f(p1.y);
        float2 f2l = h2f(p2.x), f2h = h2f(p2.y);
        float r0 = al0 * f0l.x + al1 * f1l.x + al2 * f2l.x + al3 * (a0 * dn);
        float r1 = al0 * f0l.y + al1 * f1l.y + al2 * f2l.y + al3 * (a1 * dn);
        float r2 = al0 * f0h.x + al1 * f1h.x + al2 * f2h.x + al3 * (a2 * dn);
        float r3 = al0 * f0h.y + al1 * f1h.y + al2 * f2h.y + al3 * (a3 * dn);
        __half2 o01 = __floats2half2_rn(r0, r1);
        __half2 o23 = __floats2half2_rn(r2, r3);
        uint2 out;
        out.x = *(unsigned int*)&o01;
        out.y = *(unsigned int*)&o23;
        outh[idx] = out;
    }
}

// ---- 16 lanes per TWO pairs (p and p+P/2), 8B fp16 loads, shfl reduce ----
__global__ void dot_kernel(const uint2* __restrict__ outh, const int* __restrict__ pa,
                           const int* __restrict__ pb, float* __restrict__ res, int P) {
    int t = blockIdx.x * blockDim.x + threadIdx.x;
    int g = t >> 4;
    int l = threadIdx.x & 15;
    int half = P >> 1;                 // P is even (1M)
    if (g >= half) return;
    int p0 = g, p1 = g + half;
    int a0 = pa[p0], b0 = pb[p0];
    int a1 = pa[p1], b1 = pb[p1];
    uint2 ua0 = outh[(size_t)a0 * 16 + l];
    uint2 ub0 = outh[(size_t)b0 * 16 + l];
    uint2 ua1 = outh[(size_t)a1 * 16 + l];
    uint2 ub1 = outh[(size_t)b1 * 16 + l];
    float2 fx0 = h2f(ua0.x), fx1 = h2f(ua0.y);
    float2 fy0 = h2f(ub0.x), fy1 = h2f(ub0.y);
    float s0 = fx0.x * fy0.x + fx0.y * fy0.y + fx1.x * fy1.x + fx1.y * fy1.y;
    float2 fu0 = h2f(ua1.x), fu1 = h2f(ua1.y);
    float2 fv0 = h2f(ub1.x), fv1 = h2f(ub1.y);
    float s1 = fu0.x * fv0.x + fu0.y * fv0.y + fu1.x * fv1.x + fu1.y * fv1.y;
    s0 += __shfl_xor(s0, 1, 64);
    s1 += __shfl_xor(s1, 1, 64);
    s0 += __shfl_xor(s0, 2, 64);
    s1 += __shfl_xor(s1, 2, 64);
    s0 += __shfl_xor(s0, 4, 64);
    s1 += __shfl_xor(s1, 4, 64);
    s0 += __shfl_xor(s0, 8, 64);
    s1 += __shfl_xor(s1, 8, 64);
    if (l == 0) {
        res[p0] = s0;
        res[p1] = s1;
    }
}

extern "C" void kernel_launch(void* const* d_in, const int* in_sizes, int n_in,
                              void* d_out, int out_size, void* d_ws, size_t ws_size,
                              hipStream_t stream) {
    const float* emb   = (const float*)d_in[0];
    const float* alpha = (const float*)d_in[1];
    const int*   ei    = (const int*)d_in[2];
    const int*   eli   = (const int*)d_in[3];
    const int* row = ei;                // edge_index[0] = source
    const int* col = ei + N_EDGES;      // edge_index[1] = target
    const int* pa  = eli;
    const int* pb  = eli + N_PAIRS;
    float* res = (float*)d_out;

    const size_t hfeat_bytes = (size_t)N_NODES * DIM * sizeof(__half); // 25.6 MB
    char* ws = (char*)d_ws;
    size_t off = 0;
    auto alloc = [&](size_t bytes) {
        void* p = ws + off;
        off += (bytes + 255) & ~(size_t)255;
        return p;
    };
    int*      bktcntA  = (int*)alloc((size_t)NBC * BSTRIDE * sizeof(int));
    unsigned* stagingA = (unsigned*)alloc((size_t)NBC * BKTCAPA * sizeof(unsigned)); // 13.6 MB
    int*      srcrow   = (int*)alloc((size_t)N_NODES * CAP * sizeof(int));           // 38.4 MB (reused as ew)
    int*      deg      = (int*)alloc((size_t)N_NODES * sizeof(int));
    float*    dinv     = (float*)alloc((size_t)N_NODES * sizeof(float));
    __half*   h0       = (__half*)alloc(hfeat_bytes);
    __half*   h1       = (__half*)alloc(hfeat_bytes);
    __half*   h2       = (__half*)alloc(hfeat_bytes);
    __half*   outh     = (__half*)alloc(hfeat_bytes);
    unsigned int* ew = (unsigned int*)srcrow;   // in-place repack

    // ---- CSR build: coarse partition + fused fine-filter/LDS-tile build + ew pack ----
    hipMemsetAsync(bktcntA, 0, (size_t)NBC * BSTRIDE * sizeof(int), stream);
    partA_kernel<<<NBLKA, 256, 0, stream>>>(row, col, bktcntA, stagingA, N_EDGES);
    build_kernel<<<NB, 256, 0, stream>>>(stagingA, bktcntA, srcrow, deg, dinv, N_NODES);
    const int total_slots = N_NODES * CAP;
    ewpack_kernel<<<(total_slots + 255) / 256, 256, 0, stream>>>(ew, deg, total_slots);

    // ---- emb -> fp16 h0 ----
    const int n2 = N_NODES * DIM / 2;
    convert_kernel<<<(n2 + 255) / 256, 256, 0, stream>>>((const float2*)emb, (__half2*)h0, n2);

    // ---- 3 propagation layers; layer 3 fuses the alpha-combine ----
    const int prop_grid = N_NODES / 4;   // 4 waves/block, 1 node/wave
    prop_kernel<<<prop_grid, 256, 0, stream>>>((const uint2*)h0, ew, deg, dinv, (uint2*)h1, N_NODES);
    prop_kernel<<<prop_grid, 256, 0, stream>>>((const uint2*)h1, ew, deg, dinv, (uint2*)h2, N_NODES);
    prop_final_kernel<<<prop_grid, 256, 0, stream>>>((const uint2*)h2, ew, deg, dinv,
                                                     (const uint2*)h0, (const uint2*)h1,
                                                     alpha, (uint2*)outh, N_NODES);

    // ---- pair dot products on fp16 rows (2 pairs / 16-lane group) ----
    dot_kernel<<<((size_t)(N_PAIRS / 2) * 16 + 255) / 256, 256, 0, stream>>>(
        (const uint2*)outh, pa, pb, res, N_PAIRS);
}

// Round 14
// 376.628 us; speedup vs baseline: 1.2133x; 1.1466x over previous
//
#include <hip/hip_runtime.h>
#include <hip/hip_fp16.h>

#define N_NODES 200000
#define N_EDGES 3200000
#define N_PAIRS 1000000
#define DIM 64
#define CAP 48                  // slots per node (max degree ~38 for Poisson(16))
#define NPB 256                 // nodes per fine bucket  (fine bucket = col >> 8)
#define NB 782                  // ceil(N_NODES / NPB)
#define BKTCAP 5120             // fine staging capacity per bucket
#define BSTRIDE 16              // padded counters: one per 64B line

// two-level partition
#define CBITS 11
#define NBC 98                  // ceil(200000 / 2048) coarse buckets
#define BKTCAPA 34816           // coarse staging cap (mean 32768 + 11 sigma)
#define CHUNKA 4096
#define NBLKA ((N_EDGES + CHUNKA - 1) / CHUNKA)   // 782
#define BUFB 4400               // >= ceil(BKTCAPA/8)

// ---- pass A: counting-sort 4096 edges by coarse bucket, coalesced streamout ----
__global__ void partA_kernel(const int* __restrict__ row, const int* __restrict__ col,
                             int* __restrict__ bktcntA, unsigned* __restrict__ stagingA, int E) {
    __shared__ unsigned buf[CHUNKA];          // 16 KB
    __shared__ int cntA[128], offA[128];
    __shared__ int curA[NBC], baseA[NBC];
    int tid = threadIdx.x;
    for (int i = tid; i < 128; i += 256) cntA[i] = 0;
    __syncthreads();
    int start = blockIdx.x * CHUNKA;
    unsigned pk[16];
    int bk[16];
    #pragma unroll
    for (int k = 0; k < 16; ++k) {
        int e = start + k * 256 + tid;
        if (e < E) {
            int c = col[e];
            int r = row[e];
            pk[k] = ((unsigned)(c & 2047) << 18) | (unsigned)r;   // col_local(11b) | row(18b)
            bk[k] = c >> CBITS;
            atomicAdd(&cntA[bk[k]], 1);
        } else bk[k] = -1;
    }
    __syncthreads();
    // inclusive scan over 128 (Hillis-Steele), then exclusive
    if (tid < 128) offA[tid] = cntA[tid];
    __syncthreads();
    for (int d = 1; d < 128; d <<= 1) {
        int v = 0;
        if (tid < 128 && tid >= d) v = offA[tid - d];
        __syncthreads();
        if (tid < 128) offA[tid] += v;
        __syncthreads();
    }
    if (tid < NBC) {
        int x = offA[tid] - cntA[tid];        // exclusive offset
        curA[tid] = x;
        offA[tid] = x;
        baseA[tid] = (cntA[tid] > 0) ? atomicAdd(&bktcntA[tid * BSTRIDE], cntA[tid]) : 0;
    }
    __syncthreads();
    #pragma unroll
    for (int k = 0; k < 16; ++k) {
        if (bk[k] >= 0) {
            int p = atomicAdd(&curA[bk[k]], 1);
            buf[p] = pk[k];
        }
    }
    __syncthreads();
    // coalesced per-bucket streamout (runs avg ~42 elements)
    for (int b = 0; b < NBC; ++b) {
        int n = cntA[b];
        if (n == 0) continue;
        int base = baseA[b];
        if (base + n > BKTCAPA) n = max(0, BKTCAPA - base);
        unsigned* dst = stagingA + (size_t)b * BKTCAPA + base;
        const int o = offA[b];
        for (int i = tid; i < n; i += 256) dst[i] = buf[o + i];
    }
}

// ---- pass B: slice a coarse bucket, 3-bit sort to 8 fine buckets, coalesced out ----
__global__ void partB_kernel(const unsigned* __restrict__ stagingA, const int* __restrict__ bktcntA,
                             int* __restrict__ bktcntB, unsigned* __restrict__ stagingB) {
    __shared__ unsigned buf[BUFB];            // 17.6 KB
    __shared__ int cntB[8], offB[8], curB[8], baseB[8];
    int bc = blockIdx.x >> 3;
    int s  = blockIdx.x & 7;
    int tid = threadIdx.x;
    if (tid < 8) cntB[tid] = 0;
    __syncthreads();
    int cnt = min(bktcntA[bc * BSTRIDE], BKTCAPA);
    int slice = (cnt + 7) >> 3;
    int lo = s * slice;
    int hi = min(lo + slice, cnt);
    int n = max(hi - lo, 0);                  // <= 4352 < BUFB
    const unsigned* src = stagingA + (size_t)bc * BKTCAPA + lo;
    for (int i = tid; i < n; i += 256) atomicAdd(&cntB[src[i] >> 26], 1);
    __syncthreads();
    if (tid == 0) {
        int a = 0;
        for (int b = 0; b < 8; ++b) { offB[b] = a; a += cntB[b]; }
    }
    __syncthreads();
    if (tid < 8) {
        curB[tid] = offB[tid];
        baseB[tid] = (cntB[tid] > 0) ? atomicAdd(&bktcntB[(bc * 8 + tid) * BSTRIDE], cntB[tid]) : 0;
    }
    __syncthreads();
    for (int i = tid; i < n; i += 256) {
        unsigned e = src[i];
        int fb = e >> 26;
        int p = atomicAdd(&curB[fb], 1);
        buf[p] = e & 0x3FFFFFFu;              // keep col&255 (bits 18..25) | row
    }
    __syncthreads();
    for (int b = 0; b < 8; ++b) {
        int m = cntB[b];
        if (m == 0) continue;
        int base = baseB[b];
        if (base + m > BKTCAP) m = max(0, BKTCAP - base);
        unsigned* dst = stagingB + (size_t)(bc * 8 + b) * BKTCAP + base;
        const int o = offB[b];
        for (int i = tid; i < m; i += 256) dst[i] = buf[o + i];
    }
}

// ---- pass 2: one block per fine bucket; scatter staged edges into an LDS tile ----
__global__ void build_kernel(const unsigned* __restrict__ staging, const int* __restrict__ bktcnt,
                             int* __restrict__ srcrow, int* __restrict__ deg,
                             float* __restrict__ dinv, int N) {
    __shared__ int tile[NPB * CAP];   // 48 KB
    __shared__ int cur[NPB];
    int b = blockIdx.x;
    for (int i = threadIdx.x; i < NPB; i += 256) cur[i] = 0;
    __syncthreads();
    int cnt = min(bktcnt[b * BSTRIDE], BKTCAP);
    const unsigned* st = staging + (size_t)b * BKTCAP;
    for (int i = threadIdx.x; i < cnt; i += 256) {
        unsigned packed = st[i];
        int r = packed & 0x3FFFF;
        int cl = packed >> 18;
        int p = atomicAdd(&cur[cl], 1);
        if (p < CAP) tile[cl * CAP + p] = r;
    }
    __syncthreads();
    int nodeBase = b * NPB;
    int nvalid = min(NPB, N - nodeBase);
    for (int i = threadIdx.x; i < nvalid; i += 256) {
        int d = min(cur[i], CAP);
        deg[nodeBase + i] = d;
        dinv[nodeBase + i] = (d > 0) ? rsqrtf((float)d) : 0.0f;
    }
    int tot = nvalid * CAP;
    int* dst = srcrow + (size_t)nodeBase * CAP;
    for (int i = threadIdx.x; i < tot; i += 256) dst[i] = tile[i];
}

// ---- one-time pack: ew[s] = src_id | (in_deg(src) << 18); 0 for padding slots. ----
__global__ void ewpack_kernel(unsigned int* __restrict__ ew, const int* __restrict__ deg,
                              int total) {
    int s = blockIdx.x * blockDim.x + threadIdx.x;
    if (s >= total) return;
    int n = s / CAP;
    int l = s - n * CAP;
    unsigned int e = 0;
    if (l < deg[n]) {
        int r = (int)ew[s];                    // srcrow id
        e = (unsigned int)r | ((unsigned int)deg[r] << 18);
    }
    ew[s] = e;
}

// ---- emb fp32 -> fp16 ----
__global__ void convert_kernel(const float2* __restrict__ x, __half2* __restrict__ y, int n2) {
    int i = blockIdx.x * blockDim.x + threadIdx.x;
    if (i < n2) {
        float2 v = x[i];
        y[i] = __floats2half2_rn(v.x, v.y);
    }
}

__device__ __forceinline__ float2 h2f(unsigned int u) {
    __half2 h = *(__half2*)&u;
    return __half22float2(h);
}

// ---- propagation: one wave per node; 16 lanes per row (4 dims each, uint2 load);
//      4 edges concurrent via quarter-wave groups; (id,w) broadcast from LDS. ----
__global__ void prop_kernel(const uint2* __restrict__ x, const unsigned int* __restrict__ ew,
                            const int* __restrict__ deg, const float* __restrict__ dinv,
                            uint2* __restrict__ xn, int N) {
    __shared__ int2 lds[4][CAP];          // 1.5 KB
    int wv = threadIdx.x >> 6;
    int n = blockIdx.x * 4 + wv;
    int l = threadIdx.x & 63;
    int q = l & 15;
    int quarter = l >> 4;
    int cnt = deg[n];
    if (l < CAP) {
        unsigned int e = ew[(unsigned int)n * CAP + l];
        int id = e & 0x3FFFF;
        int dr = e >> 18;
        float w = dr ? rsqrtf((float)dr) : 0.0f;
        lds[wv][l] = make_int2(id, __float_as_int(w));
    }
    __syncthreads();
    float a0 = 0.f, a1 = 0.f, a2 = 0.f, a3 = 0.f;
    int trips = (cnt + 3) >> 2;
    #pragma unroll 4
    for (int k = 0; k < trips; ++k) {
        int2 e = lds[wv][k * 4 + quarter];
        float w = __int_as_float(e.y);
        uint2 pix = x[(unsigned int)e.x * 16u + q];
        float2 flo = h2f(pix.x);
        float2 fhi = h2f(pix.y);
        a0 += flo.x * w; a1 += flo.y * w;
        a2 += fhi.x * w; a3 += fhi.y * w;
    }
    a0 += __shfl_xor(a0, 16, 64); a1 += __shfl_xor(a1, 16, 64);
    a2 += __shfl_xor(a2, 16, 64); a3 += __shfl_xor(a3, 16, 64);
    a0 += __shfl_xor(a0, 32, 64); a1 += __shfl_xor(a1, 32, 64);
    a2 += __shfl_xor(a2, 32, 64); a3 += __shfl_xor(a3, 32, 64);
    float dn = dinv[n];
    if (quarter == 0) {
        __half2 o01 = __floats2half2_rn(a0 * dn, a1 * dn);
        __half2 o23 = __floats2half2_rn(a2 * dn, a3 * dn);
        uint2 out;
        out.x = *(unsigned int*)&o01;
        out.y = *(unsigned int*)&o23;
        xn[(unsigned int)n * 16u + q] = out;
    }
}

// ---- layer-3 propagation with fused alpha-combine epilogue ----
__global__ void prop_final_kernel(const uint2* __restrict__ x, const unsigned int* __restrict__ ew,
                                  const int* __restrict__ deg, const float* __restrict__ dinv,
                                  const uint2* __restrict__ h0, const uint2* __restrict__ h1,
                                  const float* __restrict__ alpha,
                                  uint2* __restrict__ outh, int N) {
    __shared__ int2 lds[4][CAP];
    int wv = threadIdx.x >> 6;
    int n = blockIdx.x * 4 + wv;
    int l = threadIdx.x & 63;
    int q = l & 15;
    int quarter = l >> 4;
    int cnt = deg[n];
    if (l < CAP) {
        unsigned int e = ew[(unsigned int)n * CAP + l];
        int id = e & 0x3FFFF;
        int dr = e >> 18;
        float w = dr ? rsqrtf((float)dr) : 0.0f;
        lds[wv][l] = make_int2(id, __float_as_int(w));
    }
    __syncthreads();
    float a0 = 0.f, a1 = 0.f, a2 = 0.f, a3 = 0.f;
    int trips = (cnt + 3) >> 2;
    #pragma unroll 4
    for (int k = 0; k < trips; ++k) {
        int2 e = lds[wv][k * 4 + quarter];
        float w = __int_as_float(e.y);
        uint2 pix = x[(unsigned int)e.x * 16u + q];
        float2 flo = h2f(pix.x);
        float2 fhi = h2f(pix.y);
        a0 += flo.x * w; a1 += flo.y * w;
        a2 += fhi.x * w; a3 += fhi.y * w;
    }
    a0 += __shfl_xor(a0, 16, 64); a1 += __shfl_xor(a1, 16, 64);
    a2 += __shfl_xor(a2, 16, 64); a3 += __shfl_xor(a3, 16, 64);
    a0 += __shfl_xor(a0, 32, 64); a1 += __shfl_xor(a1, 32, 64);
    a2 += __shfl_xor(a2, 32, 64); a3 += __shfl_xor(a3, 32, 64);
    float dn = dinv[n];
    if (quarter == 0) {
        float al0 = alpha[0], al1 = alpha[1], al2 = alpha[2], al3 = alpha[3];
        unsigned int idx = (unsigned int)n * 16u + q;
        uint2 p0 = h0[idx];
        uint2 p1 = h1[idx];
        uint2 p2 = x[idx];
        float2 f0l = h2f(p0.x), f0h = h2f(p0.y);
        float2 f1l = h2f(p1.x), f1h = h2f(p1.y);
        float2 f2l = h2f(p2.x), f2h = h2f(p2.y);
        float r0 = al0 * f0l.x + al1 * f1l.x + al2 * f2l.x + al3 * (a0 * dn);
        float r1 = al0 * f0l.y + al1 * f1l.y + al2 * f2l.y + al3 * (a1 * dn);
        float r2 = al0 * f0h.x + al1 * f1h.x + al2 * f2h.x + al3 * (a2 * dn);
        float r3 = al0 * f0h.y + al1 * f1h.y + al2 * f2h.y + al3 * (a3 * dn);
        __half2 o01 = __floats2half2_rn(r0, r1);
        __half2 o23 = __floats2half2_rn(r2, r3);
        uint2 out;
        out.x = *(unsigned int*)&o01;
        out.y = *(unsigned int*)&o23;
        outh[idx] = out;
    }
}

// ---- 16 lanes per TWO pairs (p and p+P/2), 8B fp16 loads, shfl reduce ----
__global__ void dot_kernel(const uint2* __restrict__ outh, const int* __restrict__ pa,
                           const int* __restrict__ pb, float* __restrict__ res, int P) {
    int t = blockIdx.x * blockDim.x + threadIdx.x;
    int g = t >> 4;
    int l = threadIdx.x & 15;
    int half = P >> 1;                 // P is even (1M)
    if (g >= half) return;
    int p0 = g, p1 = g + half;
    int a0 = pa[p0], b0 = pb[p0];
    int a1 = pa[p1], b1 = pb[p1];
    uint2 ua0 = outh[(size_t)a0 * 16 + l];
    uint2 ub0 = outh[(size_t)b0 * 16 + l];
    uint2 ua1 = outh[(size_t)a1 * 16 + l];
    uint2 ub1 = outh[(size_t)b1 * 16 + l];
    float2 fx0 = h2f(ua0.x), fx1 = h2f(ua0.y);
    float2 fy0 = h2f(ub0.x), fy1 = h2f(ub0.y);
    float s0 = fx0.x * fy0.x + fx0.y * fy0.y + fx1.x * fy1.x + fx1.y * fy1.y;
    float2 fu0 = h2f(ua1.x), fu1 = h2f(ua1.y);
    float2 fv0 = h2f(ub1.x), fv1 = h2f(ub1.y);
    float s1 = fu0.x * fv0.x + fu0.y * fv0.y + fu1.x * fv1.x + fu1.y * fv1.y;
    s0 += __shfl_xor(s0, 1, 64);
    s1 += __shfl_xor(s1, 1, 64);
    s0 += __shfl_xor(s0, 2, 64);
    s1 += __shfl_xor(s1, 2, 64);
    s0 += __shfl_xor(s0, 4, 64);
    s1 += __shfl_xor(s1, 4, 64);
    s0 += __shfl_xor(s0, 8, 64);
    s1 += __shfl_xor(s1, 8, 64);
    if (l == 0) {
        res[p0] = s0;
        res[p1] = s1;
    }
}

extern "C" void kernel_launch(void* const* d_in, const int* in_sizes, int n_in,
                              void* d_out, int out_size, void* d_ws, size_t ws_size,
                              hipStream_t stream) {
    const float* emb   = (const float*)d_in[0];
    const float* alpha = (const float*)d_in[1];
    const int*   ei    = (const int*)d_in[2];
    const int*   eli   = (const int*)d_in[3];
    const int* row = ei;                // edge_index[0] = source
    const int* col = ei + N_EDGES;      // edge_index[1] = target
    const int* pa  = eli;
    const int* pb  = eli + N_PAIRS;
    float* res = (float*)d_out;

    const size_t hfeat_bytes = (size_t)N_NODES * DIM * sizeof(__half); // 25.6 MB
    char* ws = (char*)d_ws;
    size_t off = 0;
    auto alloc = [&](size_t bytes) {
        void* p = ws + off;
        off += (bytes + 255) & ~(size_t)255;
        return p;
    };
    int*      bktcntA  = (int*)alloc((size_t)NBC * BSTRIDE * sizeof(int));
    int*      bktcntB  = (int*)alloc((size_t)NB * BSTRIDE * sizeof(int));
    unsigned* stagingA = (unsigned*)alloc((size_t)NBC * BKTCAPA * sizeof(unsigned)); // 13.6 MB
    unsigned* stagingB = (unsigned*)alloc((size_t)NB * BKTCAP * sizeof(unsigned));   // 16 MB
    int*      srcrow   = (int*)alloc((size_t)N_NODES * CAP * sizeof(int));           // 38.4 MB (reused as ew)
    int*      deg      = (int*)alloc((size_t)N_NODES * sizeof(int));
    float*    dinv     = (float*)alloc((size_t)N_NODES * sizeof(float));
    __half*   h0       = (__half*)alloc(hfeat_bytes);
    __half*   h1       = (__half*)alloc(hfeat_bytes);
    __half*   h2       = (__half*)alloc(hfeat_bytes);
    __half*   outh     = (__half*)alloc(hfeat_bytes);
    unsigned int* ew = (unsigned int*)srcrow;   // in-place repack

    // ---- CSR build: 2-level coalesced partition + LDS-tile scatter + ew pack ----
    hipMemsetAsync(bktcntA, 0, (size_t)NBC * BSTRIDE * sizeof(int), stream);
    hipMemsetAsync(bktcntB, 0, (size_t)NB * BSTRIDE * sizeof(int), stream);
    partA_kernel<<<NBLKA, 256, 0, stream>>>(row, col, bktcntA, stagingA, N_EDGES);
    partB_kernel<<<NBC * 8, 256, 0, stream>>>(stagingA, bktcntA, bktcntB, stagingB);
    build_kernel<<<NB, 256, 0, stream>>>(stagingB, bktcntB, srcrow, deg, dinv, N_NODES);
    const int total_slots = N_NODES * CAP;
    ewpack_kernel<<<(total_slots + 255) / 256, 256, 0, stream>>>(ew, deg, total_slots);

    // ---- emb -> fp16 h0 ----
    const int n2 = N_NODES * DIM / 2;
    convert_kernel<<<(n2 + 255) / 256, 256, 0, stream>>>((const float2*)emb, (__half2*)h0, n2);

    // ---- 3 propagation layers; layer 3 fuses the alpha-combine ----
    const int prop_grid = N_NODES / 4;   // 4 waves/block, 1 node/wave
    prop_kernel<<<prop_grid, 256, 0, stream>>>((const uint2*)h0, ew, deg, dinv, (uint2*)h1, N_NODES);
    prop_kernel<<<prop_grid, 256, 0, stream>>>((const uint2*)h1, ew, deg, dinv, (uint2*)h2, N_NODES);
    prop_final_kernel<<<prop_grid, 256, 0, stream>>>((const uint2*)h2, ew, deg, dinv,
                                                     (const uint2*)h0, (const uint2*)h1,
                                                     alpha, (uint2*)outh, N_NODES);

    // ---- pair dot products on fp16 rows (2 pairs / 16-lane group) ----
    dot_kernel<<<((size_t)(N_PAIRS / 2) * 16 + 255) / 256, 256, 0, stream>>>(
        (const uint2*)outh, pa, pb, res, N_PAIRS);
}